// Round 13
// baseline (398.039 us; speedup 1.0000x reference)
//
#include <hip/hip_runtime.h>
#include <hip/hip_bf16.h>

// Fused LayerNorm + QKV projection for B=4, S=2048, H=2048 (fp32 in/out).
//
// Round 13 (= rounds 11/12 resubmitted after back-to-back infra failures):
// 256x128 tile, 4 waves (2Mx2N, wave-tile 128x64 = same per-wave
// geometry/acc as r3-r10), BK=32, 48 KiB LDS dbuf -> 2 independent
// blocks/CU. r3/r6/r10 proved a single 8-wave barrier domain serializes the
// LDS pipe (~726 cyc/phase) against the matrix pipe (~621): phase = sum
// (1563 cyc, MfmaUtil 35%). Two unsynced blocks per CU let one block's
// read/stage window overlap the other's MFMA burst. launch_bounds(256,2):
// 256 regs/wave, need ~190 -> no spill (r5/r7/r8 failure mode excluded).
// Counted vmcnt(2) ledger; VM0 tail at the last pair; XCD-bijective swizzle.

#define HD   2048            // hidden dim (K)
#define MTOT 8192            // B*S rows
#define NTOT 6144            // 3*H packed output cols
#define BM   256
#define BN   128
#define NKT  64              // K-tiles of BK=32

typedef __attribute__((ext_vector_type(8))) _Float16 f16x8;   // 4 VGPR
typedef __attribute__((ext_vector_type(4))) _Float16 f16x4;
typedef __attribute__((ext_vector_type(4))) float f32x4;

// ---------------------------------------------------------------------------
// Kernel 1: LayerNorm -> fp16.  One block per row, 256 threads, 8 elems each.
// ---------------------------------------------------------------------------
__global__ __launch_bounds__(256) void ln_f16_kernel(
    const float* __restrict__ x, const float* __restrict__ gamma,
    const float* __restrict__ beta, _Float16* __restrict__ hi) {
  const int row = blockIdx.x;
  const float* xr = x + (size_t)row * HD;
  const int t = threadIdx.x;

  float4 v0 = reinterpret_cast<const float4*>(xr)[t * 2];
  float4 v1 = reinterpret_cast<const float4*>(xr)[t * 2 + 1];
  float xs[8] = {v0.x, v0.y, v0.z, v0.w, v1.x, v1.y, v1.z, v1.w};

  float s = 0.f, q = 0.f;
#pragma unroll
  for (int j = 0; j < 8; ++j) { s += xs[j]; q += xs[j] * xs[j]; }
#pragma unroll
  for (int off = 32; off; off >>= 1) {
    s += __shfl_down(s, off);
    q += __shfl_down(q, off);
  }
  __shared__ float red[8];
  const int wid = t >> 6, lane = t & 63;
  if (lane == 0) { red[wid] = s; red[4 + wid] = q; }
  __syncthreads();
  s = red[0] + red[1] + red[2] + red[3];
  q = red[4] + red[5] + red[6] + red[7];
  const float mu  = s * (1.f / HD);
  const float var = q * (1.f / HD) - mu * mu;
  const float rs  = rsqrtf(var + 1e-5f);

  float4 g0 = reinterpret_cast<const float4*>(gamma)[t * 2];
  float4 g1 = reinterpret_cast<const float4*>(gamma)[t * 2 + 1];
  float4 b0 = reinterpret_cast<const float4*>(beta)[t * 2];
  float4 b1 = reinterpret_cast<const float4*>(beta)[t * 2 + 1];
  float gs[8] = {g0.x, g0.y, g0.z, g0.w, g1.x, g1.y, g1.z, g1.w};
  float bs[8] = {b0.x, b0.y, b0.z, b0.w, b1.x, b1.y, b1.z, b1.w};

  f16x8 hv;
#pragma unroll
  for (int j = 0; j < 8; ++j) {
    float y = (xs[j] - mu) * rs * gs[j] + bs[j];
    hv[j] = (_Float16)y;
  }
  *reinterpret_cast<f16x8*>(&hi[(size_t)row * HD + t * 8]) = hv;
}

// ---------------------------------------------------------------------------
// Kernel 2: weights -> fp16 (q, k, v stacked).
// ---------------------------------------------------------------------------
__global__ __launch_bounds__(256) void w_f16_kernel(
    const float* __restrict__ qw, const float* __restrict__ kw,
    const float* __restrict__ vw, _Float16* __restrict__ hi) {
  const int m = blockIdx.y;
  const float* src = (m == 0) ? qw : (m == 1) ? kw : vw;
  const size_t base = (size_t)m * HD * HD;
  const int total4 = HD * HD / 4;
  for (int i = blockIdx.x * blockDim.x + threadIdx.x; i < total4;
       i += gridDim.x * blockDim.x) {
    float4 v = reinterpret_cast<const float4*>(src)[i];
    f16x4 hv;
    hv[0] = (_Float16)v.x; hv[1] = (_Float16)v.y;
    hv[2] = (_Float16)v.z; hv[3] = (_Float16)v.w;
    *reinterpret_cast<f16x4*>(&hi[base + (size_t)i * 4]) = hv;
  }
}

// ---------------------------------------------------------------------------
// Kernel 3: 256x128 fp16 GEMM, BK=32, 4 waves, 2 blocks/CU.
// out[m][n] = sum_k A[m][k] * W_p[n][k] + bias_p[n]
//
// LDS (48 KiB, f16 units): A bufs @ {0, 8192} (16 KB each: [4kb][256][8]),
// B bufs @ {16384, 20480} (8 KB each: [4kb][128][8]).  Chunk (kb,row) holds
// X[row][kt*32 + kb*8 .. +8]: linear for global_load_lds, conflict-free
// ds_read_b128 (same pattern as r1-r10: 0 conflicts measured).
//
// Phases (2 per K-tile j, buf = j&1), pair loop i: kt0=2i (buf0), kt1 (buf1):
//   a(j): stage stA(j+1 -> buf^1)[4 gloads]; BLOAD(4)+ALOAD mh0(4);
//         16 MFMA; LGKM0; BAR
//   b(j): stage stB(j+2 -> buf)[2 gloads]; ALOAD mh1(4);
//         16 MFMA; LGKM0; VM2; BAR
// vmcnt ledger (per-wave instr: stA=4, stB=2):
//   at b(j)'s VM2, in-flight = {stB(j+1)[2], stA(j+1)[4], stB(j+2)[2]};
//   <=2 outstanding proves stB(j+1)+stA(j+1) landed = buf(j+1) complete.
//   Last pair (i=31): b(62) uses VM0 (skipped stB(64) breaks the VM2 proof:
//   VM2 would leave 2 of stA(63) unproven); a(63)/b(63) stage nothing.
// WAR: each region's overwrite issues >=1 barrier after its last read+LGKM0.
// ---------------------------------------------------------------------------
__device__ __forceinline__ void gload16(const _Float16* g, _Float16* l) {
  __builtin_amdgcn_global_load_lds(
      (const __attribute__((address_space(1))) void*)g,
      (__attribute__((address_space(3))) void*)l, 16, 0, 0);
}

#define BAR()   asm volatile("s_barrier" ::: "memory")
#define LGKM0() asm volatile("s_waitcnt lgkmcnt(0)" ::: "memory")
#define VM2()   asm volatile("s_waitcnt vmcnt(2)" ::: "memory")
#define VM0()   asm volatile("s_waitcnt vmcnt(0)" ::: "memory")

#define LAx(BUF, X, MH) \
  (*(const f16x8*)(lds + (BUF)*8192 + rA + (MH)*512 + (X)*128))
#define LBx(BUF, NR) \
  (*(const f16x8*)(lds + 16384 + (BUF)*4096 + rB + (NR)*128))

#define BLOAD(BUF) do { \
    bfr[0]=LBx(BUF,0); bfr[1]=LBx(BUF,1); \
    bfr[2]=LBx(BUF,2); bfr[3]=LBx(BUF,3); \
  } while (0)
#define ALOAD(BUF, MH) do { \
    a0=LAx(BUF,0,MH); a1=LAx(BUF,1,MH); \
    a2=LAx(BUF,2,MH); a3=LAx(BUF,3,MH); \
  } while (0)

#define MF(A, B, C) __builtin_amdgcn_mfma_f32_16x16x32_f16(A, B, C, 0, 0, 0)
#define MFMAS(MH) do { \
    __builtin_amdgcn_s_setprio(1); \
    acc[(MH)*4+0][0]=MF(a0,bfr[0],acc[(MH)*4+0][0]); \
    acc[(MH)*4+0][1]=MF(a0,bfr[1],acc[(MH)*4+0][1]); \
    acc[(MH)*4+0][2]=MF(a0,bfr[2],acc[(MH)*4+0][2]); \
    acc[(MH)*4+0][3]=MF(a0,bfr[3],acc[(MH)*4+0][3]); \
    acc[(MH)*4+1][0]=MF(a1,bfr[0],acc[(MH)*4+1][0]); \
    acc[(MH)*4+1][1]=MF(a1,bfr[1],acc[(MH)*4+1][1]); \
    acc[(MH)*4+1][2]=MF(a1,bfr[2],acc[(MH)*4+1][2]); \
    acc[(MH)*4+1][3]=MF(a1,bfr[3],acc[(MH)*4+1][3]); \
    acc[(MH)*4+2][0]=MF(a2,bfr[0],acc[(MH)*4+2][0]); \
    acc[(MH)*4+2][1]=MF(a2,bfr[1],acc[(MH)*4+2][1]); \
    acc[(MH)*4+2][2]=MF(a2,bfr[2],acc[(MH)*4+2][2]); \
    acc[(MH)*4+2][3]=MF(a2,bfr[3],acc[(MH)*4+2][3]); \
    acc[(MH)*4+3][0]=MF(a3,bfr[0],acc[(MH)*4+3][0]); \
    acc[(MH)*4+3][1]=MF(a3,bfr[1],acc[(MH)*4+3][1]); \
    acc[(MH)*4+3][2]=MF(a3,bfr[2],acc[(MH)*4+3][2]); \
    acc[(MH)*4+3][3]=MF(a3,bfr[3],acc[(MH)*4+3][3]); \
    __builtin_amdgcn_s_setprio(0); \
  } while (0)

__global__ __launch_bounds__(256, 2) void qkv_gemm_kernel(
    const _Float16* __restrict__ Ah, const _Float16* __restrict__ Wh,
    const float* __restrict__ qb, const float* __restrict__ kb,
    const float* __restrict__ vb, float* __restrict__ out) {
  extern __shared__ _Float16 lds[];   // 49152 B

  const int t    = threadIdx.x;
  const int lane = t & 63;
  const int wid  = t >> 6;            // 0..3
  const int wm   = wid >> 1;          // 0..1 (M)
  const int wn   = wid & 1;           // 0..1 (N)
  const int fr   = lane & 15;
  const int fq   = lane >> 4;

  // Bijective XCD swizzle: 1536 wgs = 8 x 192.  Each XCD owns 4 contiguous
  // M-rows (4 x 512KB A-panels = 2 MB in its private L2), all 48 N-blocks.
  const int orig = blockIdx.y * gridDim.x + blockIdx.x;
  const int wg   = (orig & 7) * 192 + (orig >> 3);
  const int bx   = wg % 48;
  const int by   = wg / 48;

  const int n0  = bx * BN;
  const int m0  = by * BM;
  const int p   = n0 >> 11;
  const int ln0 = n0 & (HD - 1);
  const _Float16* Ag = Ah + (size_t)m0 * HD;
  const _Float16* Bg = Wh + (size_t)p * HD * HD + (size_t)ln0 * HD;
  const float* bias = (p == 0) ? qb : (p == 1) ? kb : vb;

  // Fragment-read invariants (f16 offsets within a buffer).
  const int rA = fq * 2048 + wm * 1024 + fr * 8;
  const int rB = fq * 1024 + wn * 512 + fr * 8;

  // Staging: A-tile 256x32 (16KB, 4 gloads/thread), B-tile 128x32 (8KB, 2).
  // Chunk c = q*256 + t: LDS offset c*16B (wave-linear: base + lane*16B).
  const int rowB = t & 127, kqB = t >> 7;
  auto stA = [&](int buf, int kt) {
    const _Float16* g = Ag + (size_t)t * HD + kt * 32;
    _Float16* l = lds + buf * 8192 + t * 8;
#pragma unroll
    for (int q = 0; q < 4; ++q) gload16(g + q * 8, l + q * 2048);
  };
  auto stB = [&](int buf, int kt) {
    const _Float16* g = Bg + (size_t)rowB * HD + kt * 32 + kqB * 8;
    _Float16* l = lds + 16384 + buf * 4096 + t * 8;
#pragma unroll
    for (int q = 0; q < 2; ++q) gload16(g + q * 16, l + q * 2048);
  };

  f32x4 acc[8][4] = {};

  // Prologue: buf0 <- kt0 (A+B), buf1 <- kt1 (B only; A staged at a(0)).
  // VM2: in-flight = stB(1,1)[2] -> stA(0,0)+stB(0,0) landed = buf0 ready.
  stA(0, 0); stB(0, 0); stB(1, 1);
  VM2();
  BAR();

#pragma unroll 1
  for (int i = 0; i < NKT / 2; ++i) {
    const int kt0 = 2 * i, kt1 = 2 * i + 1;
    const bool nl = (i < NKT / 2 - 1);
    f16x8 bfr[4];
    f16x8 a0, a1, a2, a3;

    // ---- a(kt0): buf0, mh0 ----
    stA(1, kt0 + 1);                       // kt0+1 <= 63 always
    BLOAD(0); ALOAD(0, 0);
    MFMAS(0);
    LGKM0(); BAR();

    // ---- b(kt0): buf0, mh1 ----
    if (nl) stB(0, kt0 + 2);
    ALOAD(0, 1);
    MFMAS(1);
    LGKM0();
    if (nl) { VM2(); } else { VM0(); }     // buf1@kt1 proven ready
    BAR();

    // ---- a(kt1): buf1, mh0 ----
    if (nl) stA(0, kt1 + 1);
    BLOAD(1); ALOAD(1, 0);
    MFMAS(0);
    LGKM0(); BAR();

    // ---- b(kt1): buf1, mh1 ----
    if (nl) stB(1, kt1 + 2);
    ALOAD(1, 1);
    MFMAS(1);
    LGKM0();
    if (nl) { VM2(); }                     // buf0@kt1+1 proven ready
    BAR();
  }

  // Epilogue: C/D layout col = lane&15, row = (lane>>4)*4 + reg.
  float bv[4];
#pragma unroll
  for (int nr = 0; nr < 4; ++nr)
    bv[nr] = bias[(ln0 + wn * 64 + nr * 16 + fr)];
#pragma unroll
  for (int mr = 0; mr < 8; ++mr) {
    const int r0 = m0 + wm * 128 + mr * 16 + fq * 4;
#pragma unroll
    for (int nr = 0; nr < 4; ++nr) {
      const int cg = n0 + wn * 64 + nr * 16 + fr;
      f32x4 v = acc[mr][nr];
#pragma unroll
      for (int r = 0; r < 4; ++r)
        out[(size_t)(r0 + r) * NTOT + cg] = v[r] + bv[nr];
    }
  }
}

// ---------------------------------------------------------------------------
extern "C" void kernel_launch(void* const* d_in, const int* in_sizes, int n_in,
                              void* d_out, int out_size, void* d_ws,
                              size_t ws_size, hipStream_t stream) {
  const float* x     = (const float*)d_in[0];
  const float* gamma = (const float*)d_in[1];
  const float* beta  = (const float*)d_in[2];
  const float* qw    = (const float*)d_in[3];
  const float* qb    = (const float*)d_in[4];
  const float* kw    = (const float*)d_in[5];
  const float* kbia  = (const float*)d_in[6];
  const float* vw    = (const float*)d_in[7];
  const float* vb    = (const float*)d_in[8];
  float* out = (float*)d_out;

  // Workspace: [0, 32M) normed fp16 [8192][2048]; [32M, 56M) W fp16 [3][2048][2048]
  char* ws = (char*)d_ws;
  _Float16* Ahp = (_Float16*)(ws);
  _Float16* Whp = (_Float16*)(ws + (size_t)MTOT * HD * 2);

  (void)hipFuncSetAttribute((const void*)qkv_gemm_kernel,
                            hipFuncAttributeMaxDynamicSharedMemorySize, 49152);

  ln_f16_kernel<<<MTOT, 256, 0, stream>>>(x, gamma, beta, Ahp);
  w_f16_kernel<<<dim3(1024, 3), 256, 0, stream>>>(qw, kw, vw, Whp);
  qkv_gemm_kernel<<<dim3(NTOT / BN, MTOT / BM), 256, 49152, stream>>>(
      Ahp, Whp, qb, kbia, vb, out);
}

// Round 14
// 286.589 us; speedup vs baseline: 1.3889x; 1.3889x over previous
//
#include <hip/hip_runtime.h>
#include <hip/hip_bf16.h>

// Fused LayerNorm + QKV projection for B=4, S=2048, H=2048 (fp32 in/out).
//
// Round 14: back to 256x256/BK=64/8-wave (r13's 2-block split regressed 1.57x
// tracking its 1.5x staged-bytes/FLOP). This round ports the m201 template's
// phase decomposition FAITHFULLY: C-quadrant phases with EVEN read
// distribution ({8,4,8,4} ds_read_b128 per phase: B-frags loaded per k-slice
// and reused across two phases) and the two-barrier phase
// [reads; stage; (vm guard); s_barrier; lgkmcnt(0); setprio MFMA; s_barrier].
// New proven ledger: stages P0(A1h1+B1h1@kt1) P3(B0h0) P4(B0h1) P5(A0h0)
// P6(A0h1) P7(B1h0+A1h0@kt3); guards VM2@P3 (drains P0 -> buf1@kt1; VM0
// final iter) and VM4@P7 (drains P3-P6 -> buf0@kt2).

#define HD   2048            // hidden dim (K)
#define MTOT 8192            // B*S rows
#define NTOT 6144            // 3*H packed output cols
#define NIT  16              // iterations (2 K-tiles of BK=64 each)

typedef __attribute__((ext_vector_type(8))) _Float16 f16x8;   // 4 VGPR
typedef __attribute__((ext_vector_type(4))) _Float16 f16x4;
typedef __attribute__((ext_vector_type(4))) float f32x4;

// ---------------------------------------------------------------------------
// Kernel 1: LayerNorm -> fp16.  One block per row, 256 threads, 8 elems each.
// ---------------------------------------------------------------------------
__global__ __launch_bounds__(256) void ln_f16_kernel(
    const float* __restrict__ x, const float* __restrict__ gamma,
    const float* __restrict__ beta, _Float16* __restrict__ hi) {
  const int row = blockIdx.x;
  const float* xr = x + (size_t)row * HD;
  const int t = threadIdx.x;

  float4 v0 = reinterpret_cast<const float4*>(xr)[t * 2];
  float4 v1 = reinterpret_cast<const float4*>(xr)[t * 2 + 1];
  float xs[8] = {v0.x, v0.y, v0.z, v0.w, v1.x, v1.y, v1.z, v1.w};

  float s = 0.f, q = 0.f;
#pragma unroll
  for (int j = 0; j < 8; ++j) { s += xs[j]; q += xs[j] * xs[j]; }
#pragma unroll
  for (int off = 32; off; off >>= 1) {
    s += __shfl_down(s, off);
    q += __shfl_down(q, off);
  }
  __shared__ float red[8];
  const int wid = t >> 6, lane = t & 63;
  if (lane == 0) { red[wid] = s; red[4 + wid] = q; }
  __syncthreads();
  s = red[0] + red[1] + red[2] + red[3];
  q = red[4] + red[5] + red[6] + red[7];
  const float mu  = s * (1.f / HD);
  const float var = q * (1.f / HD) - mu * mu;
  const float rs  = rsqrtf(var + 1e-5f);

  float4 g0 = reinterpret_cast<const float4*>(gamma)[t * 2];
  float4 g1 = reinterpret_cast<const float4*>(gamma)[t * 2 + 1];
  float4 b0 = reinterpret_cast<const float4*>(beta)[t * 2];
  float4 b1 = reinterpret_cast<const float4*>(beta)[t * 2 + 1];
  float gs[8] = {g0.x, g0.y, g0.z, g0.w, g1.x, g1.y, g1.z, g1.w};
  float bs[8] = {b0.x, b0.y, b0.z, b0.w, b1.x, b1.y, b1.z, b1.w};

  f16x8 hv;
#pragma unroll
  for (int j = 0; j < 8; ++j) {
    float y = (xs[j] - mu) * rs * gs[j] + bs[j];
    hv[j] = (_Float16)y;
  }
  *reinterpret_cast<f16x8*>(&hi[(size_t)row * HD + t * 8]) = hv;
}

// ---------------------------------------------------------------------------
// Kernel 2: weights -> fp16 (q, k, v stacked).
// ---------------------------------------------------------------------------
__global__ __launch_bounds__(256) void w_f16_kernel(
    const float* __restrict__ qw, const float* __restrict__ kw,
    const float* __restrict__ vw, _Float16* __restrict__ hi) {
  const int m = blockIdx.y;
  const float* src = (m == 0) ? qw : (m == 1) ? kw : vw;
  const size_t base = (size_t)m * HD * HD;
  const int total4 = HD * HD / 4;
  for (int i = blockIdx.x * blockDim.x + threadIdx.x; i < total4;
       i += gridDim.x * blockDim.x) {
    float4 v = reinterpret_cast<const float4*>(src)[i];
    f16x4 hv;
    hv[0] = (_Float16)v.x; hv[1] = (_Float16)v.y;
    hv[2] = (_Float16)v.z; hv[3] = (_Float16)v.w;
    *reinterpret_cast<f16x4*>(&hi[base + (size_t)i * 4]) = hv;
  }
}

// ---------------------------------------------------------------------------
// Kernel 3: 256x256 8-phase fp16 GEMM, m201-faithful even-read quadrants.
// out[m][n] = sum_k A[m][k] * W_p[n][k] + bias_p[n]
//
// LDS (128 KiB, f16): A bufs @ {0,16384}, B bufs @ {32768,49152}; buffer =
// 8 kb-planes x 256 rows x 8 f16 (linear for global_load_lds, conflict-free
// ds_read_b128 - 0 conflicts measured r1-r13).
//
// Phase = [ds_reads for THIS phase's MFMA][stage][vm guard?]
//         [s_barrier][lgkmcnt(0)][setprio 16 MFMA][s_barrier].
// Reads per phase: {8,4,8,4}x2 (B per k-slice, reused 2 phases).
// Stage slots (2 gloads per half): P0: buf1.A-h1 + buf1.B-h1 <- kt1 (current
// buf1 tile; regions last read prev-P7/prev-P6) | P3: buf0.B-h0 <- kt2 (B0
// last read P2) | P4: buf0.B-h1 | P5: buf0.A-h0 (last read P2) |
// P6: buf0.A-h1 (last read P3) | P7: buf1.B-h0 + buf1.A-h0 <- kt3 (last
// read P6).
// Guards: VM2@P3 (outstanding <=2 = P3's own; drains prev-P7 + P0 -> buf1@kt1
// complete; VM0 final iter since P3's stage is skipped) and VM4@P7
// (outstanding <=4 = P7's own; drains P3..P6 -> buf0@kt2 complete).
// WAR: each phase's lgkm0 (post-barrier) fences that phase's reads before
// its trailing barrier; every stage-issue is >=2 barriers after the target
// region's last read.
// ---------------------------------------------------------------------------
__device__ __forceinline__ void gload16(const _Float16* g, _Float16* l) {
  __builtin_amdgcn_global_load_lds(
      (const __attribute__((address_space(1))) void*)g,
      (__attribute__((address_space(3))) void*)l, 16, 0, 0);
}

#define BAR()   asm volatile("s_barrier" ::: "memory")
#define LGKM0() asm volatile("s_waitcnt lgkmcnt(0)" ::: "memory")
#define VM2()   asm volatile("s_waitcnt vmcnt(2)" ::: "memory")
#define VM4()   asm volatile("s_waitcnt vmcnt(4)" ::: "memory")
#define VM0()   asm volatile("s_waitcnt vmcnt(0)" ::: "memory")

#define LA(BUF, X, MH, KS) \
  (*(const f16x8*)(lds + (BUF)*16384 + rA + (KS)*8192 + (MH)*512 + (X)*128))
#define LB(BUF, NR, KS) \
  (*(const f16x8*)(lds + 32768 + (BUF)*16384 + rB + (KS)*8192 + (NR)*128))

#define BLK(BUF, KS) do { \
    bk[0]=LB(BUF,0,KS); bk[1]=LB(BUF,1,KS); \
    bk[2]=LB(BUF,2,KS); bk[3]=LB(BUF,3,KS); \
  } while (0)
#define ALOAD(BUF, MH, KS) do { \
    a0=LA(BUF,0,MH,KS); a1=LA(BUF,1,MH,KS); \
    a2=LA(BUF,2,MH,KS); a3=LA(BUF,3,MH,KS); \
  } while (0)

#define MF(A, B, C) __builtin_amdgcn_mfma_f32_16x16x32_f16(A, B, C, 0, 0, 0)
#define MFMAS(MH) do { \
    __builtin_amdgcn_s_setprio(1); \
    acc[(MH)*4+0][0]=MF(a0,bk[0],acc[(MH)*4+0][0]); \
    acc[(MH)*4+0][1]=MF(a0,bk[1],acc[(MH)*4+0][1]); \
    acc[(MH)*4+0][2]=MF(a0,bk[2],acc[(MH)*4+0][2]); \
    acc[(MH)*4+0][3]=MF(a0,bk[3],acc[(MH)*4+0][3]); \
    acc[(MH)*4+1][0]=MF(a1,bk[0],acc[(MH)*4+1][0]); \
    acc[(MH)*4+1][1]=MF(a1,bk[1],acc[(MH)*4+1][1]); \
    acc[(MH)*4+1][2]=MF(a1,bk[2],acc[(MH)*4+1][2]); \
    acc[(MH)*4+1][3]=MF(a1,bk[3],acc[(MH)*4+1][3]); \
    acc[(MH)*4+2][0]=MF(a2,bk[0],acc[(MH)*4+2][0]); \
    acc[(MH)*4+2][1]=MF(a2,bk[1],acc[(MH)*4+2][1]); \
    acc[(MH)*4+2][2]=MF(a2,bk[2],acc[(MH)*4+2][2]); \
    acc[(MH)*4+2][3]=MF(a2,bk[3],acc[(MH)*4+2][3]); \
    acc[(MH)*4+3][0]=MF(a3,bk[0],acc[(MH)*4+3][0]); \
    acc[(MH)*4+3][1]=MF(a3,bk[1],acc[(MH)*4+3][1]); \
    acc[(MH)*4+3][2]=MF(a3,bk[2],acc[(MH)*4+3][2]); \
    acc[(MH)*4+3][3]=MF(a3,bk[3],acc[(MH)*4+3][3]); \
    __builtin_amdgcn_s_setprio(0); \
  } while (0)

__global__ __launch_bounds__(512, 2) void qkv_gemm_kernel(
    const _Float16* __restrict__ Ah, const _Float16* __restrict__ Wh,
    const float* __restrict__ qb, const float* __restrict__ kb,
    const float* __restrict__ vb, float* __restrict__ out) {
  extern __shared__ _Float16 lds[];   // 131072 B

  const int t    = threadIdx.x;
  const int lane = t & 63;
  const int wid  = t >> 6;            // 0..7
  const int wm   = wid >> 2;          // 0..1 (M)
  const int wn   = wid & 3;           // 0..3 (N)
  const int fr   = lane & 15;
  const int fq   = lane >> 4;

  const int n0  = blockIdx.x * 256;
  const int m0  = blockIdx.y * 256;
  const int p   = n0 >> 11;
  const int ln0 = n0 & (HD - 1);
  const _Float16* Ag  = Ah + (size_t)m0 * HD;
  const _Float16* Bgp = Wh + (size_t)p * HD * HD + (size_t)ln0 * HD;
  const float* bias = (p == 0) ? qb : (p == 1) ? kb : vb;

  // staging invariants: wave-linear dest (chunk = kb0*256 + rowbase + lane)
  const int kb0     = t >> 7;                         // 0..3
  const int rowbase = (t & 63) + ((t & 64) << 1);     // lane + (wid&1)*128
  const size_t goff = (size_t)rowbase * HD + kb0 * 8; // global f16 offset
  const int ldsC    = kb0 * 256 + rowbase;            // lds chunk

  // fragment-read invariants (f16 offsets within a buffer)
  const int rA = fq * 2048 + wm * 1024 + fr * 8;
  const int rB = fq * 2048 + wn * 512 + fr * 8;

  auto stA = [&](int buf, int hf, int kt) {
    const _Float16* g = Ag + goff + (size_t)(hf * 64) * HD + kt * 64;
    _Float16* l = lds + buf * 16384 + (ldsC + hf * 64) * 8;
    gload16(g, l); gload16(g + 32, l + 8192);
  };
  auto stB = [&](int buf, int hf, int kt) {
    const _Float16* g = Bgp + goff + (size_t)(hf * 64) * HD + kt * 64;
    _Float16* l = lds + 32768 + buf * 16384 + (ldsC + hf * 64) * 8;
    gload16(g, l); gload16(g + 32, l + 8192);
  };

  f32x4 acc[8][4] = {};

  // Prologue: buf0 <- kt0 complete (8 gloads), buf1 <- kt1 h0-halves
  // (B1h0+A1h0, 4 gloads).  VM4 leaves the pair in flight -> buf0 proven.
  stB(0, 0, 0); stB(0, 1, 0); stA(0, 0, 0); stA(0, 1, 0);
  stB(1, 0, 1); stA(1, 0, 1);
  VM4();
  BAR();

#pragma unroll 1
  for (int i = 0; i < NIT; ++i) {
    const bool nl = (i < NIT - 1);
    const int kt1 = 2 * i + 1, kt2 = 2 * i + 2, kt3 = 2 * i + 3;
    f16x8 bk[4];
    f16x8 a0, a1, a2, a3;

    // ---- P0: buf0 (mh0,ks0); reads 8; stage buf1 h1-halves @ kt1 ----
    BLK(0, 0); ALOAD(0, 0, 0);
    stA(1, 1, kt1); stB(1, 1, kt1);
    BAR(); LGKM0();
    MFMAS(0); BAR();

    // ---- P1: buf0 (mh1,ks0); reads 4 ----
    ALOAD(0, 1, 0);
    BAR(); LGKM0();
    MFMAS(1); BAR();

    // ---- P2: buf0 (mh0,ks1); reads 8 ----
    BLK(0, 1); ALOAD(0, 0, 1);
    BAR(); LGKM0();
    MFMAS(0); BAR();

    // ---- P3: buf0 (mh1,ks1); stage B0h0@kt2; guard buf1@kt1 ----
    ALOAD(0, 1, 1);
    if (nl) { stB(0, 0, kt2); VM2(); } else { VM0(); }
    BAR(); LGKM0();
    MFMAS(1); BAR();

    // ---- P4: buf1 (mh0,ks0); reads 8; stage B0h1@kt2 ----
    BLK(1, 0); ALOAD(1, 0, 0);
    if (nl) stB(0, 1, kt2);
    BAR(); LGKM0();
    MFMAS(0); BAR();

    // ---- P5: buf1 (mh1,ks0); stage A0h0@kt2 ----
    ALOAD(1, 1, 0);
    if (nl) stA(0, 0, kt2);
    BAR(); LGKM0();
    MFMAS(1); BAR();

    // ---- P6: buf1 (mh0,ks1); reads 8; stage A0h1@kt2 ----
    BLK(1, 1); ALOAD(1, 0, 1);
    if (nl) stA(0, 1, kt2);
    BAR(); LGKM0();
    MFMAS(0); BAR();

    // ---- P7: buf1 (mh1,ks1); stage buf1 h0-halves @ kt3; guard buf0@kt2 --
    ALOAD(1, 1, 1);
    if (nl) { stB(1, 0, kt3); stA(1, 0, kt3); VM4(); }
    BAR(); LGKM0();
    MFMAS(1); BAR();
  }

  // Epilogue: C/D layout col = lane&15, row = (lane>>4)*4 + reg.
  float bv[4];
#pragma unroll
  for (int nr = 0; nr < 4; ++nr)
    bv[nr] = bias[(ln0 + wn * 64 + nr * 16 + fr)];
#pragma unroll
  for (int mr = 0; mr < 8; ++mr) {
    const int r0 = m0 + wm * 128 + mr * 16 + fq * 4;
#pragma unroll
    for (int nr = 0; nr < 4; ++nr) {
      const int cg = n0 + wn * 64 + nr * 16 + fr;
      f32x4 v = acc[mr][nr];
#pragma unroll
      for (int r = 0; r < 4; ++r)
        out[(size_t)(r0 + r) * NTOT + cg] = v[r] + bv[nr];
    }
  }
}

// ---------------------------------------------------------------------------
extern "C" void kernel_launch(void* const* d_in, const int* in_sizes, int n_in,
                              void* d_out, int out_size, void* d_ws,
                              size_t ws_size, hipStream_t stream) {
  const float* x     = (const float*)d_in[0];
  const float* gamma = (const float*)d_in[1];
  const float* beta  = (const float*)d_in[2];
  const float* qw    = (const float*)d_in[3];
  const float* qb    = (const float*)d_in[4];
  const float* kw    = (const float*)d_in[5];
  const float* kbia  = (const float*)d_in[6];
  const float* vw    = (const float*)d_in[7];
  const float* vb    = (const float*)d_in[8];
  float* out = (float*)d_out;

  // Workspace: [0, 32M) normed fp16 [8192][2048]; [32M, 56M) W fp16 [3][2048][2048]
  char* ws = (char*)d_ws;
  _Float16* Ahp = (_Float16*)(ws);
  _Float16* Whp = (_Float16*)(ws + (size_t)MTOT * HD * 2);

  (void)hipFuncSetAttribute((const void*)qkv_gemm_kernel,
                            hipFuncAttributeMaxDynamicSharedMemorySize, 131072);

  ln_f16_kernel<<<MTOT, 256, 0, stream>>>(x, gamma, beta, Ahp);
  w_f16_kernel<<<dim3(1024, 3), 256, 0, stream>>>(qw, kw, vw, Whp);
  qkv_gemm_kernel<<<dim3(NTOT / 256, MTOT / 256), 512, 131072, stream>>>(
      Ahp, Whp, qb, kbia, vb, out);
}

// Round 15
// 230.910 us; speedup vs baseline: 1.7238x; 1.2411x over previous
//
#include <hip/hip_runtime.h>
#include <hip/hip_bf16.h>

// Fused LayerNorm + QKV projection for B=4, S=2048, H=2048 (fp32 in/out).
//
// Round 15: r6 skeleton (256x256, BK=64, 8 waves, proven stage/vmcnt ledger)
// with the LDS layout changed from subtiled [kb][row][8] (which forced
// per-lane-SCATTERED global_load_lds sources: 64 x 16B transactions/instr,
// measured wall ~0.65 req/cyc/CU across r1/r2/r6/r13) to row-major [256][64]
// with XOR swizzle (rule #21): linear LDS dest + inverse-swizzled per-lane
// GLOBAL source (line-coalesced: 8 lanes = one 128B row) + swizzled ds_read
// (term is a per-thread constant). 8x fewer global transactions.

#define HD   2048            // hidden dim (K)
#define MTOT 8192            // B*S rows
#define NTOT 6144            // 3*H packed output cols
#define NIT  16              // iterations (2 K-tiles of BK=64 each)

typedef __attribute__((ext_vector_type(8))) _Float16 f16x8;   // 4 VGPR
typedef __attribute__((ext_vector_type(4))) _Float16 f16x4;
typedef __attribute__((ext_vector_type(4))) float f32x4;

// ---------------------------------------------------------------------------
// Kernel 1: LayerNorm -> fp16.  One block per row, 256 threads, 8 elems each.
// ---------------------------------------------------------------------------
__global__ __launch_bounds__(256) void ln_f16_kernel(
    const float* __restrict__ x, const float* __restrict__ gamma,
    const float* __restrict__ beta, _Float16* __restrict__ hi) {
  const int row = blockIdx.x;
  const float* xr = x + (size_t)row * HD;
  const int t = threadIdx.x;

  float4 v0 = reinterpret_cast<const float4*>(xr)[t * 2];
  float4 v1 = reinterpret_cast<const float4*>(xr)[t * 2 + 1];
  float xs[8] = {v0.x, v0.y, v0.z, v0.w, v1.x, v1.y, v1.z, v1.w};

  float s = 0.f, q = 0.f;
#pragma unroll
  for (int j = 0; j < 8; ++j) { s += xs[j]; q += xs[j] * xs[j]; }
#pragma unroll
  for (int off = 32; off; off >>= 1) {
    s += __shfl_down(s, off);
    q += __shfl_down(q, off);
  }
  __shared__ float red[8];
  const int wid = t >> 6, lane = t & 63;
  if (lane == 0) { red[wid] = s; red[4 + wid] = q; }
  __syncthreads();
  s = red[0] + red[1] + red[2] + red[3];
  q = red[4] + red[5] + red[6] + red[7];
  const float mu  = s * (1.f / HD);
  const float var = q * (1.f / HD) - mu * mu;
  const float rs  = rsqrtf(var + 1e-5f);

  float4 g0 = reinterpret_cast<const float4*>(gamma)[t * 2];
  float4 g1 = reinterpret_cast<const float4*>(gamma)[t * 2 + 1];
  float4 b0 = reinterpret_cast<const float4*>(beta)[t * 2];
  float4 b1 = reinterpret_cast<const float4*>(beta)[t * 2 + 1];
  float gs[8] = {g0.x, g0.y, g0.z, g0.w, g1.x, g1.y, g1.z, g1.w};
  float bs[8] = {b0.x, b0.y, b0.z, b0.w, b1.x, b1.y, b1.z, b1.w};

  f16x8 hv;
#pragma unroll
  for (int j = 0; j < 8; ++j) {
    float y = (xs[j] - mu) * rs * gs[j] + bs[j];
    hv[j] = (_Float16)y;
  }
  *reinterpret_cast<f16x8*>(&hi[(size_t)row * HD + t * 8]) = hv;
}

// ---------------------------------------------------------------------------
// Kernel 2: weights -> fp16 (q, k, v stacked).
// ---------------------------------------------------------------------------
__global__ __launch_bounds__(256) void w_f16_kernel(
    const float* __restrict__ qw, const float* __restrict__ kw,
    const float* __restrict__ vw, _Float16* __restrict__ hi) {
  const int m = blockIdx.y;
  const float* src = (m == 0) ? qw : (m == 1) ? kw : vw;
  const size_t base = (size_t)m * HD * HD;
  const int total4 = HD * HD / 4;
  for (int i = blockIdx.x * blockDim.x + threadIdx.x; i < total4;
       i += gridDim.x * blockDim.x) {
    float4 v = reinterpret_cast<const float4*>(src)[i];
    f16x4 hv;
    hv[0] = (_Float16)v.x; hv[1] = (_Float16)v.y;
    hv[2] = (_Float16)v.z; hv[3] = (_Float16)v.w;
    *reinterpret_cast<f16x4*>(&hi[base + (size_t)i * 4]) = hv;
  }
}

// ---------------------------------------------------------------------------
// Kernel 3: 256x256 8-phase fp16 GEMM, row-major swizzled LDS, coalesced
// staging.  out[m][n] = sum_k A[m][k] * W_p[n][k] + bias_p[n]
//
// LDS (128 KiB, f16): A bufs @ {0,16384}, B bufs @ {32768,49152}; each buf =
// row-major [256 rows][64 f16] (128 B rows, 2048 16B-chunks).
// Swizzle (involution, 16B granular): physical slot s of row r holds logical
// k-chunk s ^ (r&7).  Staging chunk c (row c>>3, slot c&7) therefore loads
// global column ((c&7) ^ ((c>>3)&7)) -> 8 lanes still cover one 128B row =
// LINE-COALESCED.  Reads: fragment row = (16-mult) + fr, so r&7 = fr&7 and
// the swizzled k-term ((ks*4+fq) ^ (fr&7))*8 f16 is a per-thread constant;
// lanes 0-15 hit 8 distinct 16B slots (2-way aliasing = free, m136).
//
// Schedule/ledger = r6 EXACTLY (passed at 250.6 us):
//   p0: stA(1,h1,kt1) | p1: stB(0,h0,kt2) | p2: stB(0,h1,kt2) |
//   p3: stA(0,h0,kt2) +VM6 (VM0 last iter) | p4: stA(0,h1,kt2) |
//   p5: stB(1,h0,kt3) | p6: stB(1,h1,kt3) | p7: stA(1,h0,kt3) +VM6
// Stage half hf = rows {hf*64..+64} U {128+hf*64..+64} (matches the mh-row
// groups each ALOAD reads, so every r6 WAR slot proof carries over).
// ---------------------------------------------------------------------------
__device__ __forceinline__ void gload16(const _Float16* g, _Float16* l) {
  __builtin_amdgcn_global_load_lds(
      (const __attribute__((address_space(1))) void*)g,
      (__attribute__((address_space(3))) void*)l, 16, 0, 0);
}

#define BAR()   asm volatile("s_barrier" ::: "memory")
#define LGKM0() asm volatile("s_waitcnt lgkmcnt(0)" ::: "memory")
#define VM6()   asm volatile("s_waitcnt vmcnt(6)" ::: "memory")
#define VM0()   asm volatile("s_waitcnt vmcnt(0)" ::: "memory")

// f16-offset reads: row*64 + swizzled k-term (KKV = kk0 or kk1).
#define LA(BUF, X, MH, KKV) \
  (*(const f16x8*)(lds + (BUF)*16384 + rA + (MH)*4096 + (X)*1024 + (KKV)))
#define LB(BUF, NR, KKV) \
  (*(const f16x8*)(lds + 32768 + (BUF)*16384 + rB + (NR)*1024 + (KKV)))

#define BLOAD(BUF) do { \
    bfr[0][0]=LB(BUF,0,kk0); bfr[1][0]=LB(BUF,1,kk0); \
    bfr[2][0]=LB(BUF,2,kk0); bfr[3][0]=LB(BUF,3,kk0); \
    bfr[0][1]=LB(BUF,0,kk1); bfr[1][1]=LB(BUF,1,kk1); \
    bfr[2][1]=LB(BUF,2,kk1); bfr[3][1]=LB(BUF,3,kk1); \
  } while (0)
#define ALOAD(BUF, MH, KKV) do { \
    a0=LA(BUF,0,MH,KKV); a1=LA(BUF,1,MH,KKV); \
    a2=LA(BUF,2,MH,KKV); a3=LA(BUF,3,MH,KKV); \
  } while (0)

#define MM(MR, NR, AREG, KS) \
  acc[MR][NR] = __builtin_amdgcn_mfma_f32_16x16x32_f16( \
      AREG, bfr[NR][KS], acc[MR][NR], 0, 0, 0);
#define MFMAS(MH, KS) do { \
    __builtin_amdgcn_s_setprio(1); \
    MM((MH)*4+0, 0, a0, KS) MM((MH)*4+0, 1, a0, KS) \
    MM((MH)*4+0, 2, a0, KS) MM((MH)*4+0, 3, a0, KS) \
    MM((MH)*4+1, 0, a1, KS) MM((MH)*4+1, 1, a1, KS) \
    MM((MH)*4+1, 2, a1, KS) MM((MH)*4+1, 3, a1, KS) \
    MM((MH)*4+2, 0, a2, KS) MM((MH)*4+2, 1, a2, KS) \
    MM((MH)*4+2, 2, a2, KS) MM((MH)*4+2, 3, a2, KS) \
    MM((MH)*4+3, 0, a3, KS) MM((MH)*4+3, 1, a3, KS) \
    MM((MH)*4+3, 2, a3, KS) MM((MH)*4+3, 3, a3, KS) \
    __builtin_amdgcn_s_setprio(0); \
  } while (0)

__global__ __launch_bounds__(512, 2) void qkv_gemm_kernel(
    const _Float16* __restrict__ Ah, const _Float16* __restrict__ Wh,
    const float* __restrict__ qb, const float* __restrict__ kb,
    const float* __restrict__ vb, float* __restrict__ out) {
  extern __shared__ _Float16 lds[];   // 131072 B

  const int t    = threadIdx.x;
  const int lane = t & 63;
  const int wid  = t >> 6;            // 0..7
  const int wm   = wid >> 2;          // 0..1 (M)
  const int wn   = wid & 3;           // 0..3 (N)
  const int fr   = lane & 15;
  const int fq   = lane >> 4;

  const int n0  = blockIdx.x * 256;
  const int m0  = blockIdx.y * 256;
  const int p   = n0 >> 11;
  const int ln0 = n0 & (HD - 1);
  const _Float16* Ag  = Ah + (size_t)m0 * HD;
  const _Float16* Bgp = Wh + (size_t)p * HD * HD + (size_t)ln0 * HD;
  const float* bias = (p == 0) ? qb : (p == 1) ? kb : vb;

  // Staging invariants (coalesced + inverse-swizzled source):
  //   chunk-within-half c' = q*512 + t; sub-row = t>>3; slot = t&7;
  //   global k-chunk = slot ^ (sub-row & 7)  [rows hf*64+, +128 are 0 mod 8]
  const int srow = t >> 3;                              // 0..63
  const int scol = ((t & 7) ^ (srow & 7)) * 8;          // f16 offset in row
  // Fragment-read invariants: row&7 == fr&7 for every fragment row.
  const int rA  = (wm * 128 + fr) * 64;
  const int rB  = (wn * 64 + fr) * 64;
  const int kk0 = ((fq) ^ (fr & 7)) * 8;                // ks=0 k-term
  const int kk1 = ((4 + fq) ^ (fr & 7)) * 8;            // ks=1 k-term

  // stage half hf = rows {hf*64..+64} U {128+hf*64..+64}; 2 gloads/call.
  auto stA = [&](int buf, int hf, int kt) {
    const _Float16* g = Ag + (size_t)(hf * 64 + srow) * HD + kt * 64 + scol;
    _Float16* l = lds + buf * 16384 + (hf * 512 + t) * 8;
    gload16(g, l);                          // rows hf*64 + srow
    gload16(g + (size_t)128 * HD, l + 8192); // rows 128 + hf*64 + srow
  };
  auto stB = [&](int buf, int hf, int kt) {
    const _Float16* g = Bgp + (size_t)(hf * 64 + srow) * HD + kt * 64 + scol;
    _Float16* l = lds + 32768 + buf * 16384 + (hf * 512 + t) * 8;
    gload16(g, l);
    gload16(g + (size_t)128 * HD, l + 8192);
  };

  f32x4 acc[8][4] = {};

  // Prologue: buf0 <- K-tile 0 (4 halves), buf1 <- K-tile 1 (3 halves).
  // vmcnt(6) = 3 calls in flight -> buf0 fully landed.
  stB(0, 0, 0); stB(0, 1, 0); stA(0, 0, 0); stA(0, 1, 0);
  stB(1, 0, 1); stB(1, 1, 1); stA(1, 0, 1);
  VM6();
  BAR();

#pragma unroll 1
  for (int i = 0; i < NIT; ++i) {
    const bool nl = (i < NIT - 1);
    const int kt1 = 2 * i + 1, kt2 = 2 * i + 2, kt3 = 2 * i + 3;
    f16x8 bfr[4][2];
    f16x8 a0, a1, a2, a3;

    // ---- p0..p3: read buf0 (K-tile 2i) ----
    stA(1, 1, kt1);                           // p0
    ALOAD(0, 0, kk0); BLOAD(0);
    MFMAS(0, 0);
    LGKM0(); BAR();

    if (nl) stB(0, 0, kt2);                   // p1
    ALOAD(0, 0, kk1);
    MFMAS(0, 1);
    LGKM0(); BAR();

    if (nl) stB(0, 1, kt2);                   // p2
    ALOAD(0, 1, kk0);
    MFMAS(1, 0);
    LGKM0(); BAR();

    if (nl) stA(0, 0, kt2);                   // p3
    ALOAD(0, 1, kk1);
    MFMAS(1, 1);
    LGKM0();
    if (nl) { VM6(); } else { VM0(); }        // buf1 content landed
    BAR();

    // ---- p4..p7: read buf1 (K-tile 2i+1) ----
    if (nl) stA(0, 1, kt2);                   // p4
    ALOAD(1, 0, kk0); BLOAD(1);
    MFMAS(0, 0);
    LGKM0(); BAR();

    if (nl) stB(1, 0, kt3);                   // p5
    ALOAD(1, 0, kk1);
    MFMAS(0, 1);
    LGKM0(); BAR();

    if (nl) stB(1, 1, kt3);                   // p6
    ALOAD(1, 1, kk0);
    MFMAS(1, 0);
    LGKM0(); BAR();

    if (nl) stA(1, 0, kt3);                   // p7
    ALOAD(1, 1, kk1);
    MFMAS(1, 1);
    LGKM0();
    if (nl) { VM6(); }                        // buf0 content landed
    BAR();
  }

  // Epilogue: C/D layout col = lane&15, row = (lane>>4)*4 + reg.
  float bv[4];
#pragma unroll
  for (int nr = 0; nr < 4; ++nr)
    bv[nr] = bias[(ln0 + wn * 64 + nr * 16 + fr)];
#pragma unroll
  for (int mr = 0; mr < 8; ++mr) {
    const int r0 = m0 + wm * 128 + mr * 16 + fq * 4;
#pragma unroll
    for (int nr = 0; nr < 4; ++nr) {
      const int cg = n0 + wn * 64 + nr * 16 + fr;
      f32x4 v = acc[mr][nr];
#pragma unroll
      for (int r = 0; r < 4; ++r)
        out[(size_t)(r0 + r) * NTOT + cg] = v[r] + bv[nr];
    }
  }
}

// ---------------------------------------------------------------------------
extern "C" void kernel_launch(void* const* d_in, const int* in_sizes, int n_in,
                              void* d_out, int out_size, void* d_ws,
                              size_t ws_size, hipStream_t stream) {
  const float* x     = (const float*)d_in[0];
  const float* gamma = (const float*)d_in[1];
  const float* beta  = (const float*)d_in[2];
  const float* qw    = (const float*)d_in[3];
  const float* qb    = (const float*)d_in[4];
  const float* kw    = (const float*)d_in[5];
  const float* kbia  = (const float*)d_in[6];
  const float* vw    = (const float*)d_in[7];
  const float* vb    = (const float*)d_in[8];
  float* out = (float*)d_out;

  // Workspace: [0, 32M) normed fp16 [8192][2048]; [32M, 56M) W fp16 [3][2048][2048]
  char* ws = (char*)d_ws;
  _Float16* Ahp = (_Float16*)(ws);
  _Float16* Whp = (_Float16*)(ws + (size_t)MTOT * HD * 2);

  (void)hipFuncSetAttribute((const void*)qkv_gemm_kernel,
                            hipFuncAttributeMaxDynamicSharedMemorySize, 131072);

  ln_f16_kernel<<<MTOT, 256, 0, stream>>>(x, gamma, beta, Ahp);
  w_f16_kernel<<<dim3(1024, 3), 256, 0, stream>>>(qw, kw, vw, Whp);
  qkv_gemm_kernel<<<dim3(NTOT / 256, MTOT / 256), 512, 131072, stream>>>(
      Ahp, Whp, qb, kbia, vb, out);
}

// Round 16
// 228.709 us; speedup vs baseline: 1.7404x; 1.0096x over previous
//
#include <hip/hip_runtime.h>
#include <hip/hip_bf16.h>

// Fused LayerNorm + QKV projection for B=4, S=2048, H=2048 (fp32 in/out).
//
// Round 16: r15 (row-major swizzled LDS + coalesced staging, GEMM 202 us,
// MfmaUtil 46%) + one-phase A-FRAGMENT LOOKAHEAD with uniform (no-branch)
// phases: read next phase's A-frags into the alternate set (x/y) while this
// phase's MFMAs run from ready registers -> LDS pipe overlaps matrix pipe
// (r15 phase = 565 read + 621 MFMA serialized). Register budget: bfr 32 +
// x 16 + y 16 = 64 frag VGPR (+~35 addr) vs 128 available after acc - the
// r7 (96 frags) / r8 (PH branch duplication) spill causes are excluded.
// Stage slots + guards = r6/r7 proven ledger (VM6@P3 before x<-buf1,
// VM6@P7 before cross-iteration seed, VM0 tail).

#define HD   2048            // hidden dim (K)
#define MTOT 8192            // B*S rows
#define NTOT 6144            // 3*H packed output cols
#define NIT  16              // iterations (2 K-tiles of BK=64 each)

typedef __attribute__((ext_vector_type(8))) _Float16 f16x8;   // 4 VGPR
typedef __attribute__((ext_vector_type(4))) _Float16 f16x4;
typedef __attribute__((ext_vector_type(4))) float f32x4;

// ---------------------------------------------------------------------------
// Kernel 1: LayerNorm -> fp16.  One block per row, 256 threads, 8 elems each.
// ---------------------------------------------------------------------------
__global__ __launch_bounds__(256) void ln_f16_kernel(
    const float* __restrict__ x, const float* __restrict__ gamma,
    const float* __restrict__ beta, _Float16* __restrict__ hi) {
  const int row = blockIdx.x;
  const float* xr = x + (size_t)row * HD;
  const int t = threadIdx.x;

  float4 v0 = reinterpret_cast<const float4*>(xr)[t * 2];
  float4 v1 = reinterpret_cast<const float4*>(xr)[t * 2 + 1];
  float xs[8] = {v0.x, v0.y, v0.z, v0.w, v1.x, v1.y, v1.z, v1.w};

  float s = 0.f, q = 0.f;
#pragma unroll
  for (int j = 0; j < 8; ++j) { s += xs[j]; q += xs[j] * xs[j]; }
#pragma unroll
  for (int off = 32; off; off >>= 1) {
    s += __shfl_down(s, off);
    q += __shfl_down(q, off);
  }
  __shared__ float red[8];
  const int wid = t >> 6, lane = t & 63;
  if (lane == 0) { red[wid] = s; red[4 + wid] = q; }
  __syncthreads();
  s = red[0] + red[1] + red[2] + red[3];
  q = red[4] + red[5] + red[6] + red[7];
  const float mu  = s * (1.f / HD);
  const float var = q * (1.f / HD) - mu * mu;
  const float rs  = rsqrtf(var + 1e-5f);

  float4 g0 = reinterpret_cast<const float4*>(gamma)[t * 2];
  float4 g1 = reinterpret_cast<const float4*>(gamma)[t * 2 + 1];
  float4 b0 = reinterpret_cast<const float4*>(beta)[t * 2];
  float4 b1 = reinterpret_cast<const float4*>(beta)[t * 2 + 1];
  float gs[8] = {g0.x, g0.y, g0.z, g0.w, g1.x, g1.y, g1.z, g1.w};
  float bs[8] = {b0.x, b0.y, b0.z, b0.w, b1.x, b1.y, b1.z, b1.w};

  f16x8 hv;
#pragma unroll
  for (int j = 0; j < 8; ++j) {
    float y = (xs[j] - mu) * rs * gs[j] + bs[j];
    hv[j] = (_Float16)y;
  }
  *reinterpret_cast<f16x8*>(&hi[(size_t)row * HD + t * 8]) = hv;
}

// ---------------------------------------------------------------------------
// Kernel 2: weights -> fp16 (q, k, v stacked).
// ---------------------------------------------------------------------------
__global__ __launch_bounds__(256) void w_f16_kernel(
    const float* __restrict__ qw, const float* __restrict__ kw,
    const float* __restrict__ vw, _Float16* __restrict__ hi) {
  const int m = blockIdx.y;
  const float* src = (m == 0) ? qw : (m == 1) ? kw : vw;
  const size_t base = (size_t)m * HD * HD;
  const int total4 = HD * HD / 4;
  for (int i = blockIdx.x * blockDim.x + threadIdx.x; i < total4;
       i += gridDim.x * blockDim.x) {
    float4 v = reinterpret_cast<const float4*>(src)[i];
    f16x4 hv;
    hv[0] = (_Float16)v.x; hv[1] = (_Float16)v.y;
    hv[2] = (_Float16)v.z; hv[3] = (_Float16)v.w;
    *reinterpret_cast<f16x4*>(&hi[base + (size_t)i * 4]) = hv;
  }
}

// ---------------------------------------------------------------------------
// Kernel 3: 256x256 8-phase fp16 GEMM, swizzled row-major LDS, coalesced
// staging, one-phase A-lookahead.
// out[m][n] = sum_k A[m][k] * W_p[n][k] + bias_p[n]
//
// LDS (128 KiB, f16): A bufs @ {0,16384}, B bufs @ {32768,49152}; each buf =
// row-major [256][64] f16.  Swizzle: slot s of row r holds k-chunk s^(r&7);
// staging loads global column ((t&7)^((t>>3)&7)) -> line-coalesced; read
// k-terms kk0/kk1 are per-thread constants (r15, verified: 0 conflicts).
//
// Phase p: [stage][guard?][ds_reads for p+1 A-frags (+B at P0/P4)]
//          [16 MFMA from ready regs][lgkmcnt(0)][s_barrier]
// Stage slots (= r6/r15): P0:stA(1,1,kt1) P1:stB(0,0,kt2) P2:stB(0,1,kt2)
//   P3:stA(0,0,kt2) P4:stA(0,1,kt2) P5:stB(1,0,kt3) P6:stB(1,1,kt3)
//   P7:stA(1,0,kt3).
// Guards (r7-proven): VM6@P3 after stage (outstanding={P1,P2,P3}=6) proves
//   buf1@kt1 before ALOAD x<-buf1; VM0 last iter.  VM6@P7 after stage
//   (outstanding={P5,P6,P7}=6) proves buf0@kt2 before the cross-iteration
//   seed ALOAD x<-buf0.
// ---------------------------------------------------------------------------
__device__ __forceinline__ void gload16(const _Float16* g, _Float16* l) {
  __builtin_amdgcn_global_load_lds(
      (const __attribute__((address_space(1))) void*)g,
      (__attribute__((address_space(3))) void*)l, 16, 0, 0);
}

#define BAR()   asm volatile("s_barrier" ::: "memory")
#define LGKM0() asm volatile("s_waitcnt lgkmcnt(0)" ::: "memory")
#define VM6()   asm volatile("s_waitcnt vmcnt(6)" ::: "memory")
#define VM0()   asm volatile("s_waitcnt vmcnt(0)" ::: "memory")

// f16-offset reads: row*64 + swizzled k-term (KKV = kk0 or kk1).
#define LA(BUF, X, MH, KKV) \
  (*(const f16x8*)(lds + (BUF)*16384 + rA + (MH)*4096 + (X)*1024 + (KKV)))
#define LB(BUF, NR, KKV) \
  (*(const f16x8*)(lds + 32768 + (BUF)*16384 + rB + (NR)*1024 + (KKV)))

#define BLOAD(BUF) do { \
    bfr[0][0]=LB(BUF,0,kk0); bfr[1][0]=LB(BUF,1,kk0); \
    bfr[2][0]=LB(BUF,2,kk0); bfr[3][0]=LB(BUF,3,kk0); \
    bfr[0][1]=LB(BUF,0,kk1); bfr[1][1]=LB(BUF,1,kk1); \
    bfr[2][1]=LB(BUF,2,kk1); bfr[3][1]=LB(BUF,3,kk1); \
  } while (0)
#define ALD(T0, T1, T2, T3, BUF, MH, KKV) do { \
    T0 = LA(BUF, 0, MH, KKV); T1 = LA(BUF, 1, MH, KKV); \
    T2 = LA(BUF, 2, MH, KKV); T3 = LA(BUF, 3, MH, KKV); \
  } while (0)

#define MF(A, B, C) __builtin_amdgcn_mfma_f32_16x16x32_f16(A, B, C, 0, 0, 0)
#define MFMAS(A0, A1, A2, A3, MH, KS) do { \
    __builtin_amdgcn_s_setprio(1); \
    acc[(MH)*4+0][0]=MF(A0,bfr[0][KS],acc[(MH)*4+0][0]); \
    acc[(MH)*4+0][1]=MF(A0,bfr[1][KS],acc[(MH)*4+0][1]); \
    acc[(MH)*4+0][2]=MF(A0,bfr[2][KS],acc[(MH)*4+0][2]); \
    acc[(MH)*4+0][3]=MF(A0,bfr[3][KS],acc[(MH)*4+0][3]); \
    acc[(MH)*4+1][0]=MF(A1,bfr[0][KS],acc[(MH)*4+1][0]); \
    acc[(MH)*4+1][1]=MF(A1,bfr[1][KS],acc[(MH)*4+1][1]); \
    acc[(MH)*4+1][2]=MF(A1,bfr[2][KS],acc[(MH)*4+1][2]); \
    acc[(MH)*4+1][3]=MF(A1,bfr[3][KS],acc[(MH)*4+1][3]); \
    acc[(MH)*4+2][0]=MF(A2,bfr[0][KS],acc[(MH)*4+2][0]); \
    acc[(MH)*4+2][1]=MF(A2,bfr[1][KS],acc[(MH)*4+2][1]); \
    acc[(MH)*4+2][2]=MF(A2,bfr[2][KS],acc[(MH)*4+2][2]); \
    acc[(MH)*4+2][3]=MF(A2,bfr[3][KS],acc[(MH)*4+2][3]); \
    acc[(MH)*4+3][0]=MF(A3,bfr[0][KS],acc[(MH)*4+3][0]); \
    acc[(MH)*4+3][1]=MF(A3,bfr[1][KS],acc[(MH)*4+3][1]); \
    acc[(MH)*4+3][2]=MF(A3,bfr[2][KS],acc[(MH)*4+3][2]); \
    acc[(MH)*4+3][3]=MF(A3,bfr[3][KS],acc[(MH)*4+3][3]); \
    __builtin_amdgcn_s_setprio(0); \
  } while (0)

__global__ __launch_bounds__(512, 2) void qkv_gemm_kernel(
    const _Float16* __restrict__ Ah, const _Float16* __restrict__ Wh,
    const float* __restrict__ qb, const float* __restrict__ kb,
    const float* __restrict__ vb, float* __restrict__ out) {
  extern __shared__ _Float16 lds[];   // 131072 B

  const int t    = threadIdx.x;
  const int lane = t & 63;
  const int wid  = t >> 6;            // 0..7
  const int wm   = wid >> 2;          // 0..1 (M)
  const int wn   = wid & 3;           // 0..3 (N)
  const int fr   = lane & 15;
  const int fq   = lane >> 4;

  const int n0  = blockIdx.x * 256;
  const int m0  = blockIdx.y * 256;
  const int p   = n0 >> 11;
  const int ln0 = n0 & (HD - 1);
  const _Float16* Ag  = Ah + (size_t)m0 * HD;
  const _Float16* Bgp = Wh + (size_t)p * HD * HD + (size_t)ln0 * HD;
  const float* bias = (p == 0) ? qb : (p == 1) ? kb : vb;

  // Staging invariants (coalesced + inverse-swizzled source).
  const int srow = t >> 3;                              // 0..63
  const int scol = ((t & 7) ^ (srow & 7)) * 8;          // f16 offset in row
  // Fragment-read invariants.
  const int rA  = (wm * 128 + fr) * 64;
  const int rB  = (wn * 64 + fr) * 64;
  const int kk0 = ((fq) ^ (fr & 7)) * 8;
  const int kk1 = ((4 + fq) ^ (fr & 7)) * 8;

  auto stA = [&](int buf, int hf, int kt) {
    const _Float16* g = Ag + (size_t)(hf * 64 + srow) * HD + kt * 64 + scol;
    _Float16* l = lds + buf * 16384 + (hf * 512 + t) * 8;
    gload16(g, l);
    gload16(g + (size_t)128 * HD, l + 8192);
  };
  auto stB = [&](int buf, int hf, int kt) {
    const _Float16* g = Bgp + (size_t)(hf * 64 + srow) * HD + kt * 64 + scol;
    _Float16* l = lds + 32768 + buf * 16384 + (hf * 512 + t) * 8;
    gload16(g, l);
    gload16(g + (size_t)128 * HD, l + 8192);
  };

  f32x4 acc[8][4] = {};

  // Fragment registers: B set (32 VGPR) + A double sets x/y (16+16).
  f16x8 bfr[4][2];
  f16x8 x0, x1, x2, x3;
  f16x8 y0, y1, y2, y3;

  // Prologue: buf0 <- K-tile 0 (4 halves), buf1 <- K-tile 1 (3 halves).
  // vmcnt(6) = 3 calls in flight -> buf0 fully landed.
  stB(0, 0, 0); stB(0, 1, 0); stA(0, 0, 0); stA(0, 1, 0);
  stB(1, 0, 1); stB(1, 1, 1); stA(1, 0, 1);
  VM6();
  BAR();
  ALD(x0, x1, x2, x3, 0, 0, kk0);   // seed P0's A-frags (buf0 proven)

#pragma unroll 1
  for (int i = 0; i < NIT; ++i) {
    const bool nl = (i < NIT - 1);
    const int kt1 = 2 * i + 1, kt2 = 2 * i + 2, kt3 = 2 * i + 3;

    // ---- P0: MFMA buf0(mh0,ks0) from x; BLOAD(0); lookahead y<-(0,mh0,ks1)
    stA(1, 1, kt1);
    BLOAD(0);
    ALD(y0, y1, y2, y3, 0, 0, kk1);
    MFMAS(x0, x1, x2, x3, 0, 0);
    LGKM0(); BAR();

    // ---- P1: MFMA buf0(mh0,ks1) from y; lookahead x<-(0,mh1,ks0) ----
    if (nl) stB(0, 0, kt2);
    ALD(x0, x1, x2, x3, 0, 1, kk0);
    MFMAS(y0, y1, y2, y3, 0, 1);
    LGKM0(); BAR();

    // ---- P2: MFMA buf0(mh1,ks0) from x; lookahead y<-(0,mh1,ks1) ----
    if (nl) stB(0, 1, kt2);
    ALD(y0, y1, y2, y3, 0, 1, kk1);
    MFMAS(x0, x1, x2, x3, 1, 0);
    LGKM0(); BAR();

    // ---- P3: MFMA buf0(mh1,ks1) from y; guard buf1; x<-(1,mh0,ks0) ----
    if (nl) { stA(0, 0, kt2); VM6(); } else { VM0(); }
    ALD(x0, x1, x2, x3, 1, 0, kk0);
    MFMAS(y0, y1, y2, y3, 1, 1);
    LGKM0(); BAR();

    // ---- P4: MFMA buf1(mh0,ks0) from x; BLOAD(1); y<-(1,mh0,ks1) ----
    if (nl) stA(0, 1, kt2);
    BLOAD(1);
    ALD(y0, y1, y2, y3, 1, 0, kk1);
    MFMAS(x0, x1, x2, x3, 0, 0);
    LGKM0(); BAR();

    // ---- P5: MFMA buf1(mh0,ks1) from y; x<-(1,mh1,ks0) ----
    if (nl) stB(1, 0, kt3);
    ALD(x0, x1, x2, x3, 1, 1, kk0);
    MFMAS(y0, y1, y2, y3, 0, 1);
    LGKM0(); BAR();

    // ---- P6: MFMA buf1(mh1,ks0) from x; y<-(1,mh1,ks1) ----
    if (nl) stB(1, 1, kt3);
    ALD(y0, y1, y2, y3, 1, 1, kk1);
    MFMAS(x0, x1, x2, x3, 1, 0);
    LGKM0(); BAR();

    // ---- P7: MFMA buf1(mh1,ks1) from y; guard buf0@kt2; seed x ----
    if (nl) {
      stA(1, 0, kt3);
      VM6();
      ALD(x0, x1, x2, x3, 0, 0, kk0);
    }
    MFMAS(y0, y1, y2, y3, 1, 1);
    LGKM0(); BAR();
  }

  // Epilogue: C/D layout col = lane&15, row = (lane>>4)*4 + reg.
  float bv[4];
#pragma unroll
  for (int nr = 0; nr < 4; ++nr)
    bv[nr] = bias[(ln0 + wn * 64 + nr * 16 + fr)];
#pragma unroll
  for (int mr = 0; mr < 8; ++mr) {
    const int r0 = m0 + wm * 128 + mr * 16 + fq * 4;
#pragma unroll
    for (int nr = 0; nr < 4; ++nr) {
      const int cg = n0 + wn * 64 + nr * 16 + fr;
      f32x4 v = acc[mr][nr];
#pragma unroll
      for (int r = 0; r < 4; ++r)
        out[(size_t)(r0 + r) * NTOT + cg] = v[r] + bv[nr];
    }
  }
}

// ---------------------------------------------------------------------------
extern "C" void kernel_launch(void* const* d_in, const int* in_sizes, int n_in,
                              void* d_out, int out_size, void* d_ws,
                              size_t ws_size, hipStream_t stream) {
  const float* x     = (const float*)d_in[0];
  const float* gamma = (const float*)d_in[1];
  const float* beta  = (const float*)d_in[2];
  const float* qw    = (const float*)d_in[3];
  const float* qb    = (const float*)d_in[4];
  const float* kw    = (const float*)d_in[5];
  const float* kbia  = (const float*)d_in[6];
  const float* vw    = (const float*)d_in[7];
  const float* vb    = (const float*)d_in[8];
  float* out = (float*)d_out;

  // Workspace: [0, 32M) normed fp16 [8192][2048]; [32M, 56M) W fp16 [3][2048][2048]
  char* ws = (char*)d_ws;
  _Float16* Ahp = (_Float16*)(ws);
  _Float16* Whp = (_Float16*)(ws + (size_t)MTOT * HD * 2);

  (void)hipFuncSetAttribute((const void*)qkv_gemm_kernel,
                            hipFuncAttributeMaxDynamicSharedMemorySize, 131072);

  ln_f16_kernel<<<MTOT, 256, 0, stream>>>(x, gamma, beta, Ahp);
  w_f16_kernel<<<dim3(1024, 3), 256, 0, stream>>>(qw, kw, vw, Whp);
  qkv_gemm_kernel<<<dim3(NTOT / 256, MTOT / 256), 512, 131072, stream>>>(
      Ahp, Whp, qb, kbia, vb, out);
}

// Round 17
// 228.577 us; speedup vs baseline: 1.7414x; 1.0006x over previous
//
#include <hip/hip_runtime.h>
#include <hip/hip_bf16.h>

// Fused LayerNorm + QKV projection for B=4, S=2048, H=2048 (fp32 in/out).
//
// Round 17: r16 + FULL lookahead - B-fragment half-rotation through the
// existing bfr[4][2] set (zero extra registers): P7 preloads next-tile
// B-ks0, P0 preloads B-ks1, P3/P4 preload buf1's halves. Every phase's
// MFMA inputs (A and B) now come from a PRIOR phase -> reads/phase even
// out to {8,4,4,8,8,4,4,8} and no MFMA waits on same-phase LDS reads
// (r16's residual serializer: P0/P4's 12-read + same-phase-B dependency).
// Stage slots + VM6/VM0 ledger identical to r6/r15/r16 (passed 4x).

#define HD   2048            // hidden dim (K)
#define MTOT 8192            // B*S rows
#define NTOT 6144            // 3*H packed output cols
#define NIT  16              // iterations (2 K-tiles of BK=64 each)

typedef __attribute__((ext_vector_type(8))) _Float16 f16x8;   // 4 VGPR
typedef __attribute__((ext_vector_type(4))) _Float16 f16x4;
typedef __attribute__((ext_vector_type(4))) float f32x4;

// ---------------------------------------------------------------------------
// Kernel 1: LayerNorm -> fp16.  One block per row, 256 threads, 8 elems each.
// ---------------------------------------------------------------------------
__global__ __launch_bounds__(256) void ln_f16_kernel(
    const float* __restrict__ x, const float* __restrict__ gamma,
    const float* __restrict__ beta, _Float16* __restrict__ hi) {
  const int row = blockIdx.x;
  const float* xr = x + (size_t)row * HD;
  const int t = threadIdx.x;

  float4 v0 = reinterpret_cast<const float4*>(xr)[t * 2];
  float4 v1 = reinterpret_cast<const float4*>(xr)[t * 2 + 1];
  float xs[8] = {v0.x, v0.y, v0.z, v0.w, v1.x, v1.y, v1.z, v1.w};

  float s = 0.f, q = 0.f;
#pragma unroll
  for (int j = 0; j < 8; ++j) { s += xs[j]; q += xs[j] * xs[j]; }
#pragma unroll
  for (int off = 32; off; off >>= 1) {
    s += __shfl_down(s, off);
    q += __shfl_down(q, off);
  }
  __shared__ float red[8];
  const int wid = t >> 6, lane = t & 63;
  if (lane == 0) { red[wid] = s; red[4 + wid] = q; }
  __syncthreads();
  s = red[0] + red[1] + red[2] + red[3];
  q = red[4] + red[5] + red[6] + red[7];
  const float mu  = s * (1.f / HD);
  const float var = q * (1.f / HD) - mu * mu;
  const float rs  = rsqrtf(var + 1e-5f);

  float4 g0 = reinterpret_cast<const float4*>(gamma)[t * 2];
  float4 g1 = reinterpret_cast<const float4*>(gamma)[t * 2 + 1];
  float4 b0 = reinterpret_cast<const float4*>(beta)[t * 2];
  float4 b1 = reinterpret_cast<const float4*>(beta)[t * 2 + 1];
  float gs[8] = {g0.x, g0.y, g0.z, g0.w, g1.x, g1.y, g1.z, g1.w};
  float bs[8] = {b0.x, b0.y, b0.z, b0.w, b1.x, b1.y, b1.z, b1.w};

  f16x8 hv;
#pragma unroll
  for (int j = 0; j < 8; ++j) {
    float y = (xs[j] - mu) * rs * gs[j] + bs[j];
    hv[j] = (_Float16)y;
  }
  *reinterpret_cast<f16x8*>(&hi[(size_t)row * HD + t * 8]) = hv;
}

// ---------------------------------------------------------------------------
// Kernel 2: weights -> fp16 (q, k, v stacked).
// ---------------------------------------------------------------------------
__global__ __launch_bounds__(256) void w_f16_kernel(
    const float* __restrict__ qw, const float* __restrict__ kw,
    const float* __restrict__ vw, _Float16* __restrict__ hi) {
  const int m = blockIdx.y;
  const float* src = (m == 0) ? qw : (m == 1) ? kw : vw;
  const size_t base = (size_t)m * HD * HD;
  const int total4 = HD * HD / 4;
  for (int i = blockIdx.x * blockDim.x + threadIdx.x; i < total4;
       i += gridDim.x * blockDim.x) {
    float4 v = reinterpret_cast<const float4*>(src)[i];
    f16x4 hv;
    hv[0] = (_Float16)v.x; hv[1] = (_Float16)v.y;
    hv[2] = (_Float16)v.z; hv[3] = (_Float16)v.w;
    *reinterpret_cast<f16x4*>(&hi[base + (size_t)i * 4]) = hv;
  }
}

// ---------------------------------------------------------------------------
// Kernel 3: 256x256 8-phase fp16 GEMM, swizzled row-major LDS, coalesced
// staging, full (A+B) one-phase lookahead.
// out[m][n] = sum_k A[m][k] * W_p[n][k] + bias_p[n]
//
// LDS (128 KiB, f16): A bufs @ {0,16384}, B bufs @ {32768,49152}; each buf =
// row-major [256][64] f16.  Swizzle: slot s of row r holds k-chunk s^(r&7);
// staging loads global column ((t&7)^((t>>3)&7)) -> line-coalesced; read
// k-terms kk0/kk1 are per-thread constants (r15/r16-verified, 0 conflicts).
//
// Phase p: [stage][guard?][ds_reads for LATER phases][16 MFMA, inputs all
//          prior-phase][lgkmcnt(0)][s_barrier]
// Read slots/phase (per wave): P0: B0-ks1(4)+A y(4) | P1: A x(4) |
//   P2: A y(4) | P3: B1-ks0(4)+A x(4) | P4: B1-ks1(4)+A y(4) | P5: A x(4) |
//   P6: A y(4) | P7: B0'-ks0(4)+A x seed(4).
// bfr slice lifetimes: [0] written P3/P7, last read P2/P6; [1] written
//   P0/P4, last read P7/P3 - no overlap, zero extra registers.
// Stage slots (= r6/r15/r16): P0:stA(1,1,kt1) P1:stB(0,0,kt2) P2:stB(0,1,kt2)
//   P3:stA(0,0,kt2) P4:stA(0,1,kt2) P5:stB(1,0,kt3) P6:stB(1,1,kt3)
//   P7:stA(1,0,kt3).
// Guards: VM6@P3 (outstanding={P1,P2,P3}=6, proves <=P0-cur) covers P3's
//   buf1 reads (need <=P7-prev) AND P5/P6's A-mh1 reads (need P0-cur);
//   VM0 last iter.  VM6@P7 (outstanding={P5,P6,P7}=6, proves <=P4) covers
//   P7's buf0@kt2 reads (staged P1-P4).
// WAR: every region's last read >=1 barrier+LGKM0 before its stage slot
//   (re-derived for the new read schedule; all margins grew or held).
// ---------------------------------------------------------------------------
__device__ __forceinline__ void gload16(const _Float16* g, _Float16* l) {
  __builtin_amdgcn_global_load_lds(
      (const __attribute__((address_space(1))) void*)g,
      (__attribute__((address_space(3))) void*)l, 16, 0, 0);
}

#define BAR()   asm volatile("s_barrier" ::: "memory")
#define LGKM0() asm volatile("s_waitcnt lgkmcnt(0)" ::: "memory")
#define VM6()   asm volatile("s_waitcnt vmcnt(6)" ::: "memory")
#define VM0()   asm volatile("s_waitcnt vmcnt(0)" ::: "memory")

// f16-offset reads: row*64 + swizzled k-term (KKV = kk0 or kk1).
#define LA(BUF, X, MH, KKV) \
  (*(const f16x8*)(lds + (BUF)*16384 + rA + (MH)*4096 + (X)*1024 + (KKV)))
#define LB(BUF, NR, KKV) \
  (*(const f16x8*)(lds + 32768 + (BUF)*16384 + rB + (NR)*1024 + (KKV)))

// Load ONE B k-slice (4 reads) into bfr[.][SL].
#define BHALF(BUF, SL, KKV) do { \
    bfr[0][SL]=LB(BUF,0,KKV); bfr[1][SL]=LB(BUF,1,KKV); \
    bfr[2][SL]=LB(BUF,2,KKV); bfr[3][SL]=LB(BUF,3,KKV); \
  } while (0)
#define ALD(T0, T1, T2, T3, BUF, MH, KKV) do { \
    T0 = LA(BUF, 0, MH, KKV); T1 = LA(BUF, 1, MH, KKV); \
    T2 = LA(BUF, 2, MH, KKV); T3 = LA(BUF, 3, MH, KKV); \
  } while (0)

#define MF(A, B, C) __builtin_amdgcn_mfma_f32_16x16x32_f16(A, B, C, 0, 0, 0)
#define MFMAS(A0, A1, A2, A3, MH, KS) do { \
    __builtin_amdgcn_s_setprio(1); \
    acc[(MH)*4+0][0]=MF(A0,bfr[0][KS],acc[(MH)*4+0][0]); \
    acc[(MH)*4+0][1]=MF(A0,bfr[1][KS],acc[(MH)*4+0][1]); \
    acc[(MH)*4+0][2]=MF(A0,bfr[2][KS],acc[(MH)*4+0][2]); \
    acc[(MH)*4+0][3]=MF(A0,bfr[3][KS],acc[(MH)*4+0][3]); \
    acc[(MH)*4+1][0]=MF(A1,bfr[0][KS],acc[(MH)*4+1][0]); \
    acc[(MH)*4+1][1]=MF(A1,bfr[1][KS],acc[(MH)*4+1][1]); \
    acc[(MH)*4+1][2]=MF(A1,bfr[2][KS],acc[(MH)*4+1][2]); \
    acc[(MH)*4+1][3]=MF(A1,bfr[3][KS],acc[(MH)*4+1][3]); \
    acc[(MH)*4+2][0]=MF(A2,bfr[0][KS],acc[(MH)*4+2][0]); \
    acc[(MH)*4+2][1]=MF(A2,bfr[1][KS],acc[(MH)*4+2][1]); \
    acc[(MH)*4+2][2]=MF(A2,bfr[2][KS],acc[(MH)*4+2][2]); \
    acc[(MH)*4+2][3]=MF(A2,bfr[3][KS],acc[(MH)*4+2][3]); \
    acc[(MH)*4+3][0]=MF(A3,bfr[0][KS],acc[(MH)*4+3][0]); \
    acc[(MH)*4+3][1]=MF(A3,bfr[1][KS],acc[(MH)*4+3][1]); \
    acc[(MH)*4+3][2]=MF(A3,bfr[2][KS],acc[(MH)*4+3][2]); \
    acc[(MH)*4+3][3]=MF(A3,bfr[3][KS],acc[(MH)*4+3][3]); \
    __builtin_amdgcn_s_setprio(0); \
  } while (0)

__global__ __launch_bounds__(512, 2) void qkv_gemm_kernel(
    const _Float16* __restrict__ Ah, const _Float16* __restrict__ Wh,
    const float* __restrict__ qb, const float* __restrict__ kb,
    const float* __restrict__ vb, float* __restrict__ out) {
  extern __shared__ _Float16 lds[];   // 131072 B

  const int t    = threadIdx.x;
  const int lane = t & 63;
  const int wid  = t >> 6;            // 0..7
  const int wm   = wid >> 2;          // 0..1 (M)
  const int wn   = wid & 3;           // 0..3 (N)
  const int fr   = lane & 15;
  const int fq   = lane >> 4;

  const int n0  = blockIdx.x * 256;
  const int m0  = blockIdx.y * 256;
  const int p   = n0 >> 11;
  const int ln0 = n0 & (HD - 1);
  const _Float16* Ag  = Ah + (size_t)m0 * HD;
  const _Float16* Bgp = Wh + (size_t)p * HD * HD + (size_t)ln0 * HD;
  const float* bias = (p == 0) ? qb : (p == 1) ? kb : vb;

  // Staging invariants (coalesced + inverse-swizzled source).
  const int srow = t >> 3;                              // 0..63
  const int scol = ((t & 7) ^ (srow & 7)) * 8;          // f16 offset in row
  // Fragment-read invariants.
  const int rA  = (wm * 128 + fr) * 64;
  const int rB  = (wn * 64 + fr) * 64;
  const int kk0 = ((fq) ^ (fr & 7)) * 8;
  const int kk1 = ((4 + fq) ^ (fr & 7)) * 8;

  auto stA = [&](int buf, int hf, int kt) {
    const _Float16* g = Ag + (size_t)(hf * 64 + srow) * HD + kt * 64 + scol;
    _Float16* l = lds + buf * 16384 + (hf * 512 + t) * 8;
    gload16(g, l);
    gload16(g + (size_t)128 * HD, l + 8192);
  };
  auto stB = [&](int buf, int hf, int kt) {
    const _Float16* g = Bgp + (size_t)(hf * 64 + srow) * HD + kt * 64 + scol;
    _Float16* l = lds + 32768 + buf * 16384 + (hf * 512 + t) * 8;
    gload16(g, l);
    gload16(g + (size_t)128 * HD, l + 8192);
  };

  f32x4 acc[8][4] = {};

  // Fragment registers: B rotating set (32 VGPR) + A double sets x/y (16+16).
  f16x8 bfr[4][2];
  f16x8 x0, x1, x2, x3;
  f16x8 y0, y1, y2, y3;

  // Prologue: buf0 <- K-tile 0 (4 halves), buf1 <- K-tile 1 (3 halves).
  // vmcnt(6) = 3 calls in flight -> buf0 fully landed.
  stB(0, 0, 0); stB(0, 1, 0); stA(0, 0, 0); stA(0, 1, 0);
  stB(1, 0, 1); stB(1, 1, 1); stA(1, 0, 1);
  VM6();
  BAR();
  // Seed P0's inputs (buf0 proven): B0-ks0 and A(mh0,ks0).
  BHALF(0, 0, kk0);
  ALD(x0, x1, x2, x3, 0, 0, kk0);

#pragma unroll 1
  for (int i = 0; i < NIT; ++i) {
    const bool nl = (i < NIT - 1);
    const int kt1 = 2 * i + 1, kt2 = 2 * i + 2, kt3 = 2 * i + 3;

    // ---- P0: MFMA buf0(mh0,ks0); load B0-ks1 + y<-(0,mh0,ks1) ----
    stA(1, 1, kt1);
    BHALF(0, 1, kk1);
    ALD(y0, y1, y2, y3, 0, 0, kk1);
    MFMAS(x0, x1, x2, x3, 0, 0);
    LGKM0(); BAR();

    // ---- P1: MFMA buf0(mh0,ks1); x<-(0,mh1,ks0) ----
    if (nl) stB(0, 0, kt2);
    ALD(x0, x1, x2, x3, 0, 1, kk0);
    MFMAS(y0, y1, y2, y3, 0, 1);
    LGKM0(); BAR();

    // ---- P2: MFMA buf0(mh1,ks0); y<-(0,mh1,ks1) ----
    if (nl) stB(0, 1, kt2);
    ALD(y0, y1, y2, y3, 0, 1, kk1);
    MFMAS(x0, x1, x2, x3, 1, 0);
    LGKM0(); BAR();

    // ---- P3: MFMA buf0(mh1,ks1); guard buf1; load B1-ks0 + x<-(1,mh0,ks0)
    if (nl) { stA(0, 0, kt2); VM6(); } else { VM0(); }
    BHALF(1, 0, kk0);
    ALD(x0, x1, x2, x3, 1, 0, kk0);
    MFMAS(y0, y1, y2, y3, 1, 1);
    LGKM0(); BAR();

    // ---- P4: MFMA buf1(mh0,ks0); load B1-ks1 + y<-(1,mh0,ks1) ----
    if (nl) stA(0, 1, kt2);
    BHALF(1, 1, kk1);
    ALD(y0, y1, y2, y3, 1, 0, kk1);
    MFMAS(x0, x1, x2, x3, 0, 0);
    LGKM0(); BAR();

    // ---- P5: MFMA buf1(mh0,ks1); x<-(1,mh1,ks0) ----
    if (nl) stB(1, 0, kt3);
    ALD(x0, x1, x2, x3, 1, 1, kk0);
    MFMAS(y0, y1, y2, y3, 0, 1);
    LGKM0(); BAR();

    // ---- P6: MFMA buf1(mh1,ks0); y<-(1,mh1,ks1) ----
    if (nl) stB(1, 1, kt3);
    ALD(y0, y1, y2, y3, 1, 1, kk1);
    MFMAS(x0, x1, x2, x3, 1, 0);
    LGKM0(); BAR();

    // ---- P7: MFMA buf1(mh1,ks1); guard buf0@kt2; load B0'-ks0 + seed x --
    if (nl) {
      stA(1, 0, kt3);
      VM6();
      BHALF(0, 0, kk0);
      ALD(x0, x1, x2, x3, 0, 0, kk0);
    }
    MFMAS(y0, y1, y2, y3, 1, 1);
    LGKM0(); BAR();
  }

  // Epilogue: C/D layout col = lane&15, row = (lane>>4)*4 + reg.
  float bv[4];
#pragma unroll
  for (int nr = 0; nr < 4; ++nr)
    bv[nr] = bias[(ln0 + wn * 64 + nr * 16 + fr)];
#pragma unroll
  for (int mr = 0; mr < 8; ++mr) {
    const int r0 = m0 + wm * 128 + mr * 16 + fq * 4;
#pragma unroll
    for (int nr = 0; nr < 4; ++nr) {
      const int cg = n0 + wn * 64 + nr * 16 + fr;
      f32x4 v = acc[mr][nr];
#pragma unroll
      for (int r = 0; r < 4; ++r)
        out[(size_t)(r0 + r) * NTOT + cg] = v[r] + bv[nr];
    }
  }
}

// ---------------------------------------------------------------------------
extern "C" void kernel_launch(void* const* d_in, const int* in_sizes, int n_in,
                              void* d_out, int out_size, void* d_ws,
                              size_t ws_size, hipStream_t stream) {
  const float* x     = (const float*)d_in[0];
  const float* gamma = (const float*)d_in[1];
  const float* beta  = (const float*)d_in[2];
  const float* qw    = (const float*)d_in[3];
  const float* qb    = (const float*)d_in[4];
  const float* kw    = (const float*)d_in[5];
  const float* kbia  = (const float*)d_in[6];
  const float* vw    = (const float*)d_in[7];
  const float* vb    = (const float*)d_in[8];
  float* out = (float*)d_out;

  // Workspace: [0, 32M) normed fp16 [8192][2048]; [32M, 56M) W fp16 [3][2048][2048]
  char* ws = (char*)d_ws;
  _Float16* Ahp = (_Float16*)(ws);
  _Float16* Whp = (_Float16*)(ws + (size_t)MTOT * HD * 2);

  (void)hipFuncSetAttribute((const void*)qkv_gemm_kernel,
                            hipFuncAttributeMaxDynamicSharedMemorySize, 131072);

  ln_f16_kernel<<<MTOT, 256, 0, stream>>>(x, gamma, beta, Ahp);
  w_f16_kernel<<<dim3(1024, 3), 256, 0, stream>>>(qw, kw, vw, Whp);
  qkv_gemm_kernel<<<dim3(NTOT / 256, MTOT / 256), 512, 131072, stream>>>(
      Ahp, Whp, qb, kbia, vb, out);
}